// Round 10
// baseline (937.902 us; speedup 1.0000x reference)
//
#include <hip/hip_runtime.h>

#define BB 16
#define NN 4096
#define SS 1024
#define KNB 32
#define FPT 16    // points per thread in FPS (4096/256)
#define FNW 4     // waves per 256-thread FPS block

typedef unsigned long long ull;
typedef float v2f __attribute__((ext_vector_type(2)));

// exact f32 squared distance, left-to-right, no fma contraction (matches numpy)
__device__ __forceinline__ float sqd3(float dx, float dy, float dz) {
    return __fadd_rn(__fadd_rn(__fmul_rn(dx, dx), __fmul_rn(dy, dy)), __fmul_rn(dz, dz));
}

// one DPP max step on u32 (float bits of non-negative floats: u32 max == float max)
#define DPPMAX(m, ctrl, rm)                                                              \
    {                                                                                    \
        unsigned _t = (unsigned)__builtin_amdgcn_update_dpp((int)(m), (int)(m), (ctrl),  \
                                                            (rm), 0xf, false);           \
        (m) = ((m) > _t) ? (m) : _t;                                                     \
    }

// ---------------- Kernel 1: fused FPS (blocks 0..15) + P1/xyz4 (blocks 16..271) ----------
// FPS: R6 compute structure, but the per-iteration cross-wave exchange is BARRIER-FREE:
// tagged keys in parity-double-buffered LDS slots, consumed by polling. Wave skew is
// bounded <2 iterations by dataflow, so parity + 256-period tags exclude stale reads.
__global__ __launch_bounds__(256) void fused1_kernel(const float* __restrict__ xyz,
                                                     const float* __restrict__ points,
                                                     const float* __restrict__ W0,
                                                     const float* __restrict__ b0,
                                                     float* __restrict__ P1,
                                                     float4* __restrict__ xyz4,
                                                     float* __restrict__ out_newxyz) {
    __shared__ union {
        struct {
            float4 pts4[NN];          // 64 KB, 16B-aligned
            ull    keys[2][FNW];      // parity double-buffered tagged wave keys
            int    hist[SS];          // selected index per iteration
        } f;
        float w0s[67 * 64];
    } sm;

    const int t = threadIdx.x;

    if (blockIdx.x < BB) {
        // ---------------- FPS: one block per batch, 4 waves, 16 pts/thread ----------------
        const int b = blockIdx.x;
        const int lane = t & 63;
        const int wv_ = t >> 6;
        const float* src = xyz + (size_t)b * (NN * 3) + (size_t)t * (FPT * 3);

        if (t < 8) ((ull*)sm.f.keys)[t] = 0ull;   // tag 0: never matches (tags are ^0xA5)

        v2f px2[8], py2[8], pz2[8], d2[8];
        {
            float c48[48];
#pragma unroll
            for (int m = 0; m < 12; ++m) {
                float4 v = ((const float4*)src)[m];
                c48[4 * m + 0] = v.x; c48[4 * m + 1] = v.y;
                c48[4 * m + 2] = v.z; c48[4 * m + 3] = v.w;
            }
#pragma unroll
            for (int j = 0; j < 8; ++j) {
                px2[j] = (v2f){c48[6 * j + 0], c48[6 * j + 3]};
                py2[j] = (v2f){c48[6 * j + 1], c48[6 * j + 4]};
                pz2[j] = (v2f){c48[6 * j + 2], c48[6 * j + 5]};
                d2[j]  = (v2f){1e10f, 1e10f};
                sm.f.pts4[t * FPT + 2 * j + 0] = make_float4(px2[j].x, py2[j].x, pz2[j].x, 0.f);
                sm.f.pts4[t * FPT + 2 * j + 1] = make_float4(px2[j].y, py2[j].y, pz2[j].y, 0.f);
            }
        }
        __syncthreads();

        int far = 0;
        for (int it = 0; it < SS; ++it) {
            if (t == 0) sm.f.hist[it] = far;
            if (it == SS - 1) break;
            float4 c = sm.f.pts4[far];   // uniform-address b128 read (broadcast)

            // update min-dists (packed) + two-half argmax chains (exact first-index ties)
            float bv0 = -1.f, bv1 = -1.f;
            int bn0 = 0, bn1 = 0;
            {
#pragma clang fp contract(off)
                v2f cx2 = {c.x, c.x}, cy2 = {c.y, c.y}, cz2 = {c.z, c.z};
#pragma unroll
                for (int j = 0; j < 4; ++j) {      // slots 0..7
                    v2f dx = px2[j] - cx2;
                    v2f dy = py2[j] - cy2;
                    v2f dz = pz2[j] - cz2;
                    v2f s = (dx * dx + dy * dy) + dz * dz;
                    float d0 = fminf(d2[j].x, s.x);
                    float d1 = fminf(d2[j].y, s.y);
                    d2[j] = (v2f){d0, d1};
                    bool g0 = d0 > bv0; bv0 = g0 ? d0 : bv0; bn0 = g0 ? (t * FPT + 2 * j + 0) : bn0;
                    bool g1 = d1 > bv0; bv0 = g1 ? d1 : bv0; bn0 = g1 ? (t * FPT + 2 * j + 1) : bn0;
                }
#pragma unroll
                for (int j = 4; j < 8; ++j) {      // slots 8..15
                    v2f dx = px2[j] - cx2;
                    v2f dy = py2[j] - cy2;
                    v2f dz = pz2[j] - cz2;
                    v2f s = (dx * dx + dy * dy) + dz * dz;
                    float d0 = fminf(d2[j].x, s.x);
                    float d1 = fminf(d2[j].y, s.y);
                    d2[j] = (v2f){d0, d1};
                    bool g0 = d0 > bv1; bv1 = g0 ? d0 : bv1; bn1 = g0 ? (t * FPT + 2 * j + 0) : bn1;
                    bool g1 = d1 > bv1; bv1 = g1 ? d1 : bv1; bn1 = g1 ? (t * FPT + 2 * j + 1) : bn1;
                }
            }
            // merge halves: strict > keeps lower-index half on ties
            bool gm = bv1 > bv0;
            float bv = gm ? bv1 : bv0;
            int bn = gm ? bn1 : bn0;

            // wave64 DPP value-only max reduce
            unsigned mb = __float_as_uint(bv);
            DPPMAX(mb, 0x111, 0xf);  // row_shr:1
            DPPMAX(mb, 0x112, 0xf);  // row_shr:2
            DPPMAX(mb, 0x114, 0xf);  // row_shr:4
            DPPMAX(mb, 0x118, 0xf);  // row_shr:8
            DPPMAX(mb, 0x142, 0xa);  // row_bcast:15 -> rows 1,3
            DPPMAX(mb, 0x143, 0xc);  // row_bcast:31 -> rows 2,3
            unsigned vmb = (unsigned)__builtin_amdgcn_readlane((int)mb, 63);

            // earliest lane achieving the max == smallest index (contiguous ownership)
            ull ball = __ballot(__float_as_uint(bv) == vmb);
            int sel = __ffsll(ball) - 1;
            int widx = __builtin_amdgcn_readlane(bn, sel);

            // tagged key: [63:32]=value bits, [31:8]=~idx (24b), [7:0]=tag
            const int par = it & 1;
            const unsigned tg = (((unsigned)it) & 0xFFu) ^ 0xA5u;
            if (lane == 0) {
                *(volatile ull*)&sm.f.keys[par][wv_] =
                    ((ull)vmb << 32) | ((ull)((~(unsigned)widx) & 0xFFFFFFu) << 8) | (ull)tg;
            }
            // poll all 4 slots until every key carries this iteration's tag
            ull k0, k1, k2, k3;
            {
                volatile ull* kp = (volatile ull*)&sm.f.keys[par][0];
                do {
                    k0 = kp[0]; k1 = kp[1]; k2 = kp[2]; k3 = kp[3];
                } while (((((unsigned)k0 ^ tg) | ((unsigned)k1 ^ tg) |
                           ((unsigned)k2 ^ tg) | ((unsigned)k3 ^ tg)) & 0xFFu) != 0u);
            }
            // u64 max = value max, min-index tiebreak (tags equal, don't affect order)
            ull a0 = (k0 > k1) ? k0 : k1;
            ull a1 = (k2 > k3) ? k2 : k3;
            ull best = (a0 > a1) ? a0 : a1;
            far = (int)((~(unsigned)(best >> 8)) & (NN - 1));
        }
        __syncthreads();
        // write new_xyz from history
#pragma unroll
        for (int r = 0; r < 4; ++r) {
            int it2 = t + 256 * r;
            int fi = sm.f.hist[it2];
            float4 c = sm.f.pts4[fi];
            size_t o = ((size_t)b * SS + it2) * 3;
            out_newxyz[o + 0] = c.x;
            out_newxyz[o + 1] = c.y;
            out_newxyz[o + 2] = c.z;
        }
    } else {
        // ---------------- P1 + xyz4 path: 256 points per block ----------------
        for (int i = t; i < 67 * 64; i += 256) sm.w0s[i] = W0[i];
        __syncthreads();
        const int lane = t & 63;
        const int wv = t >> 6;

        // packed xyz for k3's ball query
        {
            int n0 = (blockIdx.x - BB) * 256 + t;
            xyz4[n0] = make_float4(xyz[3 * n0 + 0], xyz[3 * n0 + 1], xyz[3 * n0 + 2], 0.f);
        }

        const float bias = b0[lane];
        const int base = (blockIdx.x - BB) * 256 + wv * 64;
        for (int pi = 0; pi < 64; ++pi) {
            const int n = base + pi;  // 0 .. B*N-1
            const float* xp = xyz + (size_t)n * 3;
            const float* pp = points + (size_t)n * 64;
            float acc = bias;
            acc = fmaf(xp[0], sm.w0s[0 * 64 + lane], acc);
            acc = fmaf(xp[1], sm.w0s[1 * 64 + lane], acc);
            acc = fmaf(xp[2], sm.w0s[2 * 64 + lane], acc);
#pragma unroll 8
            for (int c = 0; c < 64; ++c) acc = fmaf(pp[c], sm.w0s[(3 + c) * 64 + lane], acc);
            P1[(size_t)n * 64 + lane] = acc;
        }
    }
}

// ---------------- Kernel 3: TWO queries per 512-thread block ----------------
// waves 0-3 = query A, waves 4-7 = query B; W2 LDS staging shared by both.
// LDS ~56 KB -> 2 blocks/CU = 4 concurrent queries/CU; launch_bounds caps VGPR at 128.
__global__ __launch_bounds__(512, 4) void k3_kernel(const float4* __restrict__ xyz4,
                                                    const float* __restrict__ P1,
                                                    const float* __restrict__ W0,
                                                    const float* __restrict__ W1,
                                                    const float* __restrict__ b1,
                                                    const float* __restrict__ W2,
                                                    const float* __restrict__ b2,
                                                    float* __restrict__ d_out) {
    const int t = threadIdx.x;
    const int lane = t & 63;
    const int wv = t >> 6;            // 0..7
    const int grp = wv >> 2;          // query group 0/1
    const int gwv = wv & 3;           // wave within group
    const int ltid = (gwv << 6) | lane;  // 0..255 within group

    __shared__ float w2t[128][68];    // W2 transposed: w2t[o][i], stride 68 dwords
    __shared__ float hs[8][8][64];    // per-wave h1, aliased as h2
    __shared__ float part[8][128];
    __shared__ int   ids[2][KNB];
    __shared__ int   bq[2][2][FNW];   // [parity][grp][gwv]

    float* out_newxyz = d_out;                                   // B*S*3
    float* out_points = d_out + (size_t)BB * SS * 3;             // B*S*128
    float* out_idx    = d_out + (size_t)BB * SS * 3 + (size_t)BB * SS * 128;  // B*S*32

    const size_t q = 2 * (size_t)blockIdx.x + grp;  // b*S + s
    const int b = (int)(q >> 10);                   // same for both groups (q0 even)
    const float nx = out_newxyz[q * 3 + 0];
    const float ny = out_newxyz[q * 3 + 1];
    const float nz = out_newxyz[q * 3 + 2];

    // ---- stage W2 -> LDS transposed (512 threads, 4 rounds). Ordered before first
    // use (L3 phase) by the query loop's barriers. ----
#pragma unroll
    for (int r = 0; r < 4; ++r) {
        int m = t + 512 * r;          // 0..2047
        int o = m & 127;
        int i4 = m >> 7;              // 0..15
        float4 v;
        v.x = W2[(4 * i4 + 0) * 128 + o];
        v.y = W2[(4 * i4 + 1) * 128 + o];
        v.z = W2[(4 * i4 + 2) * 128 + o];
        v.w = W2[(4 * i4 + 3) * 128 + o];
        *(float4*)&w2t[o][4 * i4] = v;
    }

    // ---- ball query: each group scans 256 pts/round; block-uniform exit ----
    int total = 0;
    {
        const float4* xb4 = xyz4 + (size_t)b * NN;
        const float R2 = 0.04f;  // float(0.2*0.2)
        const ull ltm = (1ull << lane) - 1ull;
        int c0 = 0, pr = 0, totalO = 0;
        float4 pc = xb4[ltid];
        while (true) {
            float4 cur = pc;
            int nc0 = c0 + 256;
            if (nc0 < NN) pc = xb4[nc0 + ltid];
            float d = sqd3(cur.x - nx, cur.y - ny, cur.z - nz);
            bool in = (d <= R2);
            ull m = __ballot(in);
            if (lane == 0) bq[pr][grp][gwv] = __popcll(m);
            __syncthreads();
            int s0 = bq[pr][grp][0], s1 = bq[pr][grp][1];
            int s2 = bq[pr][grp][2], s3 = bq[pr][grp][3];
            int o0 = bq[pr][grp ^ 1][0], o1 = bq[pr][grp ^ 1][1];
            int o2 = bq[pr][grp ^ 1][2], o3 = bq[pr][grp ^ 1][3];
            int base = total + (gwv > 0 ? s0 : 0) + (gwv > 1 ? s1 : 0) + (gwv > 2 ? s2 : 0);
            int pos = base + __popcll(m & ltm);
            if (in && pos < KNB) ids[grp][pos] = c0 + ltid;
            total  += s0 + s1 + s2 + s3;
            totalO += o0 + o1 + o2 + o3;
            c0 = nc0;
            pr ^= 1;
            bool doneM = (total >= KNB) || (c0 >= NN);
            bool doneO = (totalO >= KNB) || (c0 >= NN);
            if (doneM && doneO) break;
        }
        __syncthreads();
        int cnt = (total < KNB) ? total : KNB;
        if (ltid >= cnt && ltid < KNB) ids[grp][ltid] = ids[grp][0];  // pad (ref semantics)
    }
    __syncthreads();
    if (ltid < KNB) out_idx[q * KNB + ltid] = (float)ids[grp][ltid];

    // per-channel query projection (layer1 factorization) + W1 column (post-query)
    const float qv = nx * W0[lane] + ny * W0[64 + lane] + nz * W0[128 + lane];
    float w1col[64];
#pragma unroll
    for (int i = 0; i < 64; ++i) w1col[i] = W1[i * 64 + lane];
    const float b1v = b1[lane];

    // ---- gather + layer1: h1[k][i=lane] = relu(P1[n_k][lane] - qv) ----
    const float* P1b = P1 + (size_t)b * NN * 64;
#pragma unroll
    for (int kk = 0; kk < 8; ++kk) {
        int n = ids[grp][gwv * 8 + kk];
        float v = P1b[(size_t)n * 64 + lane] - qv;
        hs[wv][kk][lane] = fmaxf(v, 0.f);
    }

    // ---- layer2: acc[k][o=lane] = b1 + sum_i h1[k][i] * W1[i][o] ----
    float acc[8];
#pragma unroll
    for (int kk = 0; kk < 8; ++kk) acc[kk] = b1v;
#pragma unroll
    for (int qd = 0; qd < 16; ++qd) {
#pragma unroll
        for (int kk = 0; kk < 8; ++kk) {
            float4 h4 = *(const float4*)&hs[wv][kk][4 * qd];
            acc[kk] = fmaf(h4.x, w1col[4 * qd + 0], acc[kk]);
            acc[kk] = fmaf(h4.y, w1col[4 * qd + 1], acc[kk]);
            acc[kk] = fmaf(h4.z, w1col[4 * qd + 2], acc[kk]);
            acc[kk] = fmaf(h4.w, w1col[4 * qd + 3], acc[kk]);
        }
    }
    // overwrite h1 with h2 in the same LDS (same-wave ordering)
#pragma unroll
    for (int kk = 0; kk < 8; ++kk) hs[wv][kk][lane] = fmaxf(acc[kk], 0.f);

    // ---- layer3: both o-halves per qd, W2 columns streamed from LDS ----
    const float b2a = b2[lane];
    const float b2bv = b2[64 + lane];
    float acc3a[8], acc3b[8];
#pragma unroll
    for (int kk = 0; kk < 8; ++kk) { acc3a[kk] = b2a; acc3b[kk] = b2bv; }
#pragma unroll
    for (int qd = 0; qd < 16; ++qd) {
        float4 wa = *(const float4*)&w2t[lane][4 * qd];
        float4 wb = *(const float4*)&w2t[64 + lane][4 * qd];
#pragma unroll
        for (int kk = 0; kk < 8; ++kk) {
            float4 h4 = *(const float4*)&hs[wv][kk][4 * qd];
            acc3a[kk] = fmaf(h4.x, wa.x, acc3a[kk]);
            acc3a[kk] = fmaf(h4.y, wa.y, acc3a[kk]);
            acc3a[kk] = fmaf(h4.z, wa.z, acc3a[kk]);
            acc3a[kk] = fmaf(h4.w, wa.w, acc3a[kk]);
            acc3b[kk] = fmaf(h4.x, wb.x, acc3b[kk]);
            acc3b[kk] = fmaf(h4.y, wb.y, acc3b[kk]);
            acc3b[kk] = fmaf(h4.z, wb.z, acc3b[kk]);
            acc3b[kk] = fmaf(h4.w, wb.w, acc3b[kk]);
        }
    }
    float ma = 0.f, mbv = 0.f;  // relu floor: max(relu(x)) == max(0, max(x))
#pragma unroll
    for (int kk = 0; kk < 8; ++kk) {
        ma = fmaxf(ma, acc3a[kk]);
        mbv = fmaxf(mbv, acc3b[kk]);
    }
    part[wv][lane] = ma;
    part[wv][64 + lane] = mbv;
    __syncthreads();
    if (t < 256) {
        int g = t >> 7;       // 0 = query A, 1 = query B
        int ch = t & 127;
        float v = fmaxf(fmaxf(part[4 * g + 0][ch], part[4 * g + 1][ch]),
                        fmaxf(part[4 * g + 2][ch], part[4 * g + 3][ch]));
        out_points[(2 * (size_t)blockIdx.x + g) * 128 + ch] = v;
    }
}

extern "C" void kernel_launch(void* const* d_in, const int* in_sizes, int n_in,
                              void* d_out, int out_size, void* d_ws, size_t ws_size,
                              hipStream_t stream) {
    const float* xyz    = (const float*)d_in[0];
    const float* points = (const float*)d_in[1];
    const float* W0     = (const float*)d_in[2];
    const float* b0     = (const float*)d_in[3];
    const float* W1     = (const float*)d_in[4];
    const float* b1     = (const float*)d_in[5];
    const float* W2     = (const float*)d_in[6];
    const float* b2     = (const float*)d_in[7];
    float* out = (float*)d_out;
    float*  P1   = (float*)d_ws;                                        // B*N*64 f32 = 16 MB
    float4* xyz4 = (float4*)((char*)d_ws + (size_t)BB * NN * 64 * 4);   // B*N float4 = 1 MB

    // blocks 0..15: FPS (one per batch); blocks 16..271: P1+xyz4 (256 points each)
    hipLaunchKernelGGL(fused1_kernel, dim3(BB + (BB * NN) / 256), dim3(256), 0, stream,
                       xyz, points, W0, b0, P1, xyz4, out);
    // 2 queries per block
    hipLaunchKernelGGL(k3_kernel, dim3(BB * SS / 2), dim3(512), 0, stream,
                       xyz4, P1, W0, W1, b1, W2, b2, out);
}